// Round 10
// baseline (214.490 us; speedup 1.0000x reference)
//
#include <hip/hip_runtime.h>
#include <hip/hip_bf16.h>

// Problem shapes (fixed by setup_inputs)
constexpr int B_  = 4;
constexpr int N_  = 2048;
constexpr int C_  = 1024;
constexpr int H_  = 16;
constexpr int HD  = 64;    // head dim
constexpr int LR  = 20;    // low rank
constexpr int RS  = 200;   // subsample length R
constexpr int RP  = 224;   // RS padded to multiple of 32 (zero-filled)
constexpr int RPAD = 232;  // LDS row pad (29x16B rows; 2-way bank alias = free)

typedef __attribute__((ext_vector_type(8))) short bf16x8;
typedef __attribute__((ext_vector_type(4))) float f32x4;

__device__ __forceinline__ float b2f_raw(unsigned short u) {
    union { unsigned int i; float f; } v;
    v.i = ((unsigned int)u) << 16;
    return v.f;
}
__device__ __forceinline__ unsigned short f2b(float f) {
    __hip_bfloat16 h = __float2bfloat16(f);
    return *(unsigned short*)&h;
}
template <bool BF>
__device__ __forceinline__ float ldg(const void* p, size_t i) {
    if constexpr (BF) return b2f_raw(((const unsigned short*)p)[i]);
    else              return ((const float*)p)[i];
}

// async 16B global->LDS (wave-uniform LDS base; HW scatters lane i at +16*i)
__device__ __forceinline__ void async_load16(const unsigned short* g, unsigned short* l) {
    __builtin_amdgcn_global_load_lds(
        (const __attribute__((address_space(1))) unsigned int*)(const void*)g,
        (__attribute__((address_space(3))) unsigned int*)(void*)l,
        16, 0, 0);
}

// ---------------------------------------------------------------------------
// Inline dtype detect (deterministic function of x[0..1023]; all blocks in
// all kernels agree). Wave-uniform; ~4KB L2-hot read.
// ---------------------------------------------------------------------------
__device__ __forceinline__ bool detect_bf16(const unsigned int* __restrict__ x) {
    const int lane = threadIdx.x & 63;
    int cnt = 0;
    #pragma unroll
    for (int i = 0; i < 16; ++i) {
        const unsigned int w = x[lane * 16 + i];
        const unsigned int e = (w >> 7) & 0xFFu;
        cnt += (e >= 103u && e <= 140u) ? 1 : 0;
    }
    #pragma unroll
    for (int s = 1; s < 64; s <<= 1) cnt += __shfl_xor(cnt, s, 64);
    return cnt > 512;
}

// ---------------------------------------------------------------------------
// Fused prep (round 10). Grid (2048, 3):
//  y == 0: convert x (fp32->bf16, float4; skipped when bf16)
//  y == 1: convert qkw/proj_w/proj_b/cw_b, flattened (skipped when bf16)
//  y == 2: blocks 0..255 -> fused gather+wec+collapse: one block per
//          (bh, dhalf, qk) produces we2t-or-wr2t[bh][:, dhalf] DIRECTLY.
//          All operands live in LDS; the collapse MFMA uses the exact
//          fragment convention of the verified standalone collapse kernel
//          and the same ks order -> bit-identical we2t/wr2t. This deletes
//          the collapse dispatch (R9 proved it + its boundary ~ 20us)
//          WITHOUT adding work to gemm1 (R9's mistake).
// ---------------------------------------------------------------------------
struct CvtArgs {
    const void* src[5];
    unsigned short* dst[5];
    int size[5];
};

template <bool BF>
__device__ void gwc_body(const void* __restrict__ x_raw,
                         const void* __restrict__ we_raw,
                         const void* __restrict__ wr_raw,
                         const void* __restrict__ cw_raw,
                         unsigned short* __restrict__ we2t,
                         unsigned short* __restrict__ wr2t,
                         unsigned short* __restrict__ sx,   // [224*32]
                         unsigned short* __restrict__ sx2,  // [32*RPAD]
                         unsigned short* __restrict__ wl,   // [64*RPAD]
                         float* __restrict__ cwl,           // [64*20]
                         int blk) {
    const int bh    = blk >> 2;
    const int dhalf = (blk >> 1) & 1;
    const int qk    = blk & 1;
    const int b = bh >> 4;
    const int h = bh & 15;
    const int t    = threadIdx.x;
    const int wave = t >> 6;
    const int lane = t & 63;

    // (a) preload this block's cw slice as fp32 (qk selects e-offset)
    {
        const int dout = t >> 2;
        const int e0   = (t & 3) * 5;
        #pragma unroll
        for (int i = 0; i < 5; ++i)
            cwl[dout * LR + e0 + i] =
                ldg<BF>(cw_raw, (size_t)dout * 2 * LR + qk * LR + e0 + i);
    }

    // (b) gather fill into swizzled sx (verified round-6 pattern, unchanged)
    const int dlo = lane & 31;
    const int rhi = lane >> 5;     // 0/1
    for (int rd = wave; rd < 100; rd += 4) {
        const int r  = rd * 2 + rhi;
        const int ir = (r * (N_ - 1)) / (RS - 1);
        const size_t idx = ((size_t)b * N_ + ir) * C_ + h * HD + dhalf * 32 + dlo;
        unsigned short v;
        if constexpr (BF) v = ((const unsigned short*)x_raw)[idx];
        else              v = f2b(((const float*)x_raw)[idx]);
        sx[r * 32 + (dlo ^ (r & 31))] = v;
    }
    __syncthreads();   // cwl + sx ready

    // (c) wec slice: thread r=t computes wl[dout][r] = sum_e we*cw (bf16,
    //     same fp32 math + f2b as the verified wec_body -> identical bits).
    if (t < RP) {
        const int r = t;
        float w20[LR];
        if (r < RS) {
            const void* wsrc = qk ? wr_raw : we_raw;
            #pragma unroll
            for (int e = 0; e < LR; ++e)
                w20[e] = ldg<BF>(wsrc, ((size_t)h * RS + r) * LR + e);
        } else {
            #pragma unroll
            for (int e = 0; e < LR; ++e) w20[e] = 0.f;
        }
        for (int dout = 0; dout < HD; ++dout) {
            float s = 0.f;
            #pragma unroll
            for (int e = 0; e < LR; ++e) s += w20[e] * cwl[dout * LR + e];
            wl[dout * RPAD + r] = f2b(s);
        }
    }

    // (d) LDS transpose sx -> sx2[din][r] (same read addressing as the
    //     verified global writeout; zero-pads r>=RS)
    for (int o = t; o < 32 * RP; o += 256) {
        const int din = o / RP;
        const int r   = o % RP;
        const unsigned short v = (r < RS) ? sx[r * 32 + (din ^ (r & 31))]
                                          : (unsigned short)0;
        sx2[din * RPAD + r] = v;
    }
    __syncthreads();   // wl + sx2 ready

    // (e) collapse MFMA: wave w owns dout rows [w*16, w*16+16), K=224.
    //     Same fragment convention + ks order as verified collapse kernel.
    const int lq = lane >> 4;
    const int lm = lane & 15;
    f32x4 acc[2];
    acc[0] = 0.f; acc[1] = 0.f;
    for (int ks = 0; ks < RP / 32; ++ks) {
        bf16x8 av = *(const bf16x8*)&wl[(wave * 16 + lm) * RPAD + ks * 32 + lq * 8];
        #pragma unroll
        for (int j = 0; j < 2; ++j) {
            bf16x8 bv = *(const bf16x8*)&sx2[(j * 16 + lm) * RPAD + ks * 32 + lq * 8];
            acc[j] = __builtin_amdgcn_mfma_f32_16x16x32_bf16(av, bv, acc[j], 0, 0, 0);
        }
    }
    unsigned short* dst = (qk ? wr2t : we2t) + (size_t)bh * HD * HD;
    #pragma unroll
    for (int j = 0; j < 2; ++j)
        #pragma unroll
        for (int r = 0; r < 4; ++r) {
            const int dout = wave * 16 + lq * 4 + r;
            const int din  = dhalf * 32 + j * 16 + lm;
            dst[dout * HD + din] = f2b(acc[j][r]);
        }
}

__global__ __launch_bounds__(256)
void fused_prep_kernel(CvtArgs args,
                       const void* __restrict__ we_raw,
                       const void* __restrict__ wr_raw,
                       const void* __restrict__ cw_raw,
                       unsigned short* __restrict__ we2t,
                       unsigned short* __restrict__ wr2t) {
    __shared__ __align__(16) unsigned short sx[RP * 32];     // 14.0 KB
    __shared__ __align__(16) unsigned short sx2[32 * RPAD];  // 14.5 KB
    __shared__ __align__(16) unsigned short wl[64 * RPAD];   // 29.0 KB
    __shared__ float cwl[64 * LR];                           //  5.0 KB
    const bool isbf = detect_bf16((const unsigned int*)args.src[0]);
    const int y = blockIdx.y;
    if (y == 0) {
        if (isbf) return;   // zero-copy: consumers read raw bf16 directly
        const int n4 = args.size[0] >> 2;
        const int stride = 2048 * 256;
        for (int i = blockIdx.x * 256 + threadIdx.x; i < n4; i += stride) {
            const float4 v = ((const float4*)args.src[0])[i];
            ushort4 o;
            o.x = f2b(v.x); o.y = f2b(v.y); o.z = f2b(v.z); o.w = f2b(v.w);
            ((ushort4*)args.dst[0])[i] = o;
        }
    } else if (y == 1) {
        if (isbf) return;
        const int n1 = args.size[1] >> 2;
        const int n2 = args.size[2] >> 2;
        const int n3 = args.size[3] >> 2;
        const int n4 = args.size[4] >> 2;
        const int tot = n1 + n2 + n3 + n4;
        const int stride = 2048 * 256;
        for (int i = blockIdx.x * 256 + threadIdx.x; i < tot; i += stride) {
            const float4* s; ushort4* d; int j;
            if (i < n1)                { s = (const float4*)args.src[1]; d = (ushort4*)args.dst[1]; j = i; }
            else if (i < n1 + n2)      { s = (const float4*)args.src[2]; d = (ushort4*)args.dst[2]; j = i - n1; }
            else if (i < n1 + n2 + n3) { s = (const float4*)args.src[3]; d = (ushort4*)args.dst[3]; j = i - n1 - n2; }
            else                       { s = (const float4*)args.src[4]; d = (ushort4*)args.dst[4]; j = i - n1 - n2 - n3; }
            const float4 v = s[j];
            ushort4 o;
            o.x = f2b(v.x); o.y = f2b(v.y); o.z = f2b(v.z); o.w = f2b(v.w);
            d[j] = o;
        }
    } else {
        const int blk = blockIdx.x;
        if (blk >= 256) return;
        if (isbf) gwc_body<true>(args.src[0], we_raw, wr_raw, cw_raw,
                                 we2t, wr2t, sx, sx2, wl, cwl, blk);
        else      gwc_body<false>(args.src[0], we_raw, wr_raw, cw_raw,
                                  we2t, wr2t, sx, sx2, wl, cwl, blk);
    }
}

// ---------------------------------------------------------------------------
// Fused gemm1 + l2norm + score. EXACT round-6 body (verified, 51.4us).
// ---------------------------------------------------------------------------
__global__ __launch_bounds__(256, 2)
void gemm1_score_kernel(const void* __restrict__ x_raw,
                        const void* __restrict__ qkw_raw,
                        const void* __restrict__ cwb_raw,
                        const unsigned short* __restrict__ xb,
                        const unsigned short* __restrict__ qkwb,
                        const unsigned short* __restrict__ cwbb,
                        const unsigned short* __restrict__ we2t,
                        const unsigned short* __restrict__ wr2t,
                        unsigned short* __restrict__ attn) {
    constexpr int QS = 72;
    __shared__ __align__(16) unsigned short pool[32768];  // 64 KB
    unsigned short* const AsBase = pool;          // 2 x 128x64 A tiles (32 KB)
    unsigned short* const BsBase = pool + 16384;  // 2 x 128x64 B tiles (32 KB)
    unsigned short* qn = pool;                    // phase 2: 128xQS
    unsigned short* kn = pool + 128 * QS;

    const bool isbf = detect_bf16((const unsigned int*)x_raw);
    const unsigned short* xs  = isbf ? (const unsigned short*)x_raw   : xb;
    const unsigned short* qks = isbf ? (const unsigned short*)qkw_raw : qkwb;
    const unsigned short* cwb = isbf ? (const unsigned short*)cwb_raw : cwbb;

    const int t    = threadIdx.x;
    const int wave = t >> 6;
    const int lane = t & 63;
    // XCD-chunked bijective swizzle (1024 blocks, 128 per XCD)
    const int lin     = blockIdx.y * 16 + blockIdx.x;
    const int logical = (lin & 7) * 128 + (lin >> 3);
    const int h       = logical & 15;
    const int mt      = logical >> 4;       // m-tile 0..63
    const int m0      = mt * 128;
    const int K       = C_;

    const int srow  = lane >> 3;                    // 0..7
    const int sunit = (lane & 7) ^ srow;            // involutive swizzle
    const unsigned short* gA = xs + (size_t)(m0 + wave * 32 + srow) * K + sunit * 8;
    const int vb = wave * 32;                       // virtual B row 0..127
    const size_t brow = (vb < 64) ? (size_t)(h * HD + vb)
                                  : (size_t)(C_ + h * HD + (vb - 64));
    const unsigned short* gB = qks + (brow + srow) * K + sunit * 8;

    const int wr = (wave >> 1) * 64;        // row quadrant
    const int wc = (wave & 1) * 64;         // col quadrant: 0 = q, 64 = k
    const int lq = lane >> 4;
    const int lm = lane & 15;
    const int c0 = (lq ^ (lm & 7)) * 8;     // swizzled read col, ks=0

    f32x4 acc[4][4];
    #pragma unroll
    for (int i = 0; i < 4; ++i)
        #pragma unroll
        for (int j = 0; j < 4; ++j) acc[i][j] = 0.f;

    auto stage = [&](int buf) {
        unsigned short* dA = AsBase + buf * 8192 + wave * 2048;
        unsigned short* dB = BsBase + buf * 8192 + wave * 2048;
        #pragma unroll
        for (int i = 0; i < 4; ++i) {
            async_load16(gA + (size_t)i * 8 * K, dA + i * 512);
            async_load16(gB + (size_t)i * 8 * K, dB + i * 512);
        }
        gA += 64; gB += 64;
    };
    auto compute = [&](int buf) {
        const unsigned short* As = AsBase + buf * 8192;
        const unsigned short* Bs = BsBase + buf * 8192;
        #pragma unroll
        for (int ks = 0; ks < 2; ++ks) {
            const int cc = c0 ^ (ks * 32);
            bf16x8 af[4], bfr[4];
            #pragma unroll
            for (int i = 0; i < 4; ++i)
                af[i] = *(const bf16x8*)&As[(wr + i * 16 + lm) * 64 + cc];
            #pragma unroll
            for (int j = 0; j < 4; ++j)
                bfr[j] = *(const bf16x8*)&Bs[(wc + j * 16 + lm) * 64 + cc];
            #pragma unroll
            for (int i = 0; i < 4; ++i)
                #pragma unroll
                for (int j = 0; j < 4; ++j)
                    acc[i][j] = __builtin_amdgcn_mfma_f32_16x16x32_bf16(
                        af[i], bfr[j], acc[i][j], 0, 0, 0);
        }
    };

    constexpr int NTK = C_ / 64;   // 16 K-tiles
    stage(0);
    __syncthreads();
    for (int kt = 0; kt < NTK - 1; ++kt) {
        stage((kt + 1) & 1);       // prefetch next tile (other buffer)
        compute(kt & 1);           // 32 MFMA + 16 ds_read under the prefetch
        __syncthreads();           // drains vmcnt+lgkm: next tile ready, reads done
    }
    compute((NTK - 1) & 1);
    __syncthreads();               // before pool reuse by phase 2

    // ---- phase 2a: per-row l2 norm + scaled bf16 store to LDS ----
    unsigned short* dst = (wc == 0) ? qn : kn;
    #pragma unroll
    for (int i = 0; i < 4; ++i) {
        float inv[4];
        #pragma unroll
        for (int r = 0; r < 4; ++r) {
            float s = 0.f;
            #pragma unroll
            for (int j = 0; j < 4; ++j) s += acc[i][j][r] * acc[i][j][r];
            s += __shfl_xor(s, 1, 64);
            s += __shfl_xor(s, 2, 64);
            s += __shfl_xor(s, 4, 64);
            s += __shfl_xor(s, 8, 64);
            inv[r] = 1.f / fmaxf(sqrtf(s), 1e-12f);
        }
        #pragma unroll
        for (int j = 0; j < 4; ++j)
            #pragma unroll
            for (int r = 0; r < 4; ++r) {
                const int row = wr + i * 16 + lq * 4 + r;
                dst[row * QS + j * 16 + lm] = f2b(acc[i][j][r] * inv[r]);
            }
    }
    __syncthreads();

    // ---- phase 2b: attn = qn@We2T^T + kn@Wr2T^T + cw_b ----
    const int b  = mt >> 4;
    const int bh = b * H_ + h;
    const unsigned short* wq = we2t + (size_t)bh * HD * HD;
    const unsigned short* wk = wr2t + (size_t)bh * HD * HD;

    bf16x8 bq[2][4], bk[2][4];
    #pragma unroll
    for (int t2 = 0; t2 < 2; ++t2)
        #pragma unroll
        for (int j = 0; j < 4; ++j) {
            const int dout = j * 16 + lm;
            bq[t2][j] = *(const bf16x8*)&wq[dout * HD + t2 * 32 + lq * 8];
            bk[t2][j] = *(const bf16x8*)&wk[dout * HD + t2 * 32 + lq * 8];
        }

    f32x4 accS[2][4];
    #pragma unroll
    for (int rt = 0; rt < 2; ++rt)
        #pragma unroll
        for (int j = 0; j < 4; ++j) accS[rt][j] = 0.f;

    #pragma unroll
    for (int rt = 0; rt < 2; ++rt) {
        const int lr = wave * 32 + rt * 16 + lm;
        bf16x8 aq0 = *(const bf16x8*)&qn[lr * QS + lq * 8];
        bf16x8 aq1 = *(const bf16x8*)&qn[lr * QS + 32 + lq * 8];
        bf16x8 ak0 = *(const bf16x8*)&kn[lr * QS + lq * 8];
        bf16x8 ak1 = *(const bf16x8*)&kn[lr * QS + 32 + lq * 8];
        #pragma unroll
        for (int j = 0; j < 4; ++j) {
            accS[rt][j] = __builtin_amdgcn_mfma_f32_16x16x32_bf16(aq0, bq[0][j], accS[rt][j], 0, 0, 0);
            accS[rt][j] = __builtin_amdgcn_mfma_f32_16x16x32_bf16(aq1, bq[1][j], accS[rt][j], 0, 0, 0);
            accS[rt][j] = __builtin_amdgcn_mfma_f32_16x16x32_bf16(ak0, bk[0][j], accS[rt][j], 0, 0, 0);
            accS[rt][j] = __builtin_amdgcn_mfma_f32_16x16x32_bf16(ak1, bk[1][j], accS[rt][j], 0, 0, 0);
        }
    }

    #pragma unroll
    for (int rt = 0; rt < 2; ++rt)
        #pragma unroll
        for (int j = 0; j < 4; ++j) {
            const int dout = j * 16 + lm;
            const float bv = b2f_raw(cwb[dout]);
            #pragma unroll
            for (int r = 0; r < 4; ++r) {
                const int row = m0 + wave * 32 + rt * 16 + lq * 4 + r;
                attn[(size_t)row * C_ + h * HD + dout] = f2b(accS[rt][j][r] + bv);
            }
        }
}

// ---------------------------------------------------------------------------
// Output projection. EXACT round-6 body (verified).
// ---------------------------------------------------------------------------
template <bool OBF>
__device__ void mfma_gemm_body64(const unsigned short* __restrict__ A,
                                 const unsigned short* __restrict__ W,
                                 const unsigned short* __restrict__ bias,
                                 void* __restrict__ out,
                                 int M, int N, int K, int m0, int n0) {
    __shared__ __align__(16) unsigned short AsBase[16384];  // 2 x 128x64
    __shared__ __align__(16) unsigned short BsBase[16384];  // 2 x 128x64 (64 KB)

    const int t    = threadIdx.x;
    const int wave = t >> 6;
    const int lane = t & 63;

    const int srow  = lane >> 3;
    const int sunit = (lane & 7) ^ srow;
    const unsigned short* gA = A + (size_t)(m0 + wave * 32 + srow) * K + sunit * 8;
    const unsigned short* gB = W + (size_t)(n0 + wave * 32 + srow) * K + sunit * 8;

    const int wr = (wave >> 1) * 64;
    const int wc = (wave & 1) * 64;
    const int lq = lane >> 4;
    const int lm = lane & 15;
    const int c0 = (lq ^ (lm & 7)) * 8;

    f32x4 acc[4][4];
    #pragma unroll
    for (int i = 0; i < 4; ++i)
        #pragma unroll
        for (int j = 0; j < 4; ++j) acc[i][j] = 0.f;

    auto stage = [&](int buf) {
        unsigned short* dA = AsBase + buf * 8192 + wave * 2048;
        unsigned short* dB = BsBase + buf * 8192 + wave * 2048;
        #pragma unroll
        for (int i = 0; i < 4; ++i) {
            async_load16(gA + (size_t)i * 8 * K, dA + i * 512);
            async_load16(gB + (size_t)i * 8 * K, dB + i * 512);
        }
        gA += 64; gB += 64;
    };
    auto compute = [&](int buf) {
        const unsigned short* As = AsBase + buf * 8192;
        const unsigned short* Bs = BsBase + buf * 8192;
        #pragma unroll
        for (int ks = 0; ks < 2; ++ks) {
            const int cc = c0 ^ (ks * 32);
            bf16x8 af[4], bfr[4];
            #pragma unroll
            for (int i = 0; i < 4; ++i)
                af[i] = *(const bf16x8*)&As[(wr + i * 16 + lm) * 64 + cc];
            #pragma unroll
            for (int j = 0; j < 4; ++j)
                bfr[j] = *(const bf16x8*)&Bs[(wc + j * 16 + lm) * 64 + cc];
            #pragma unroll
            for (int i = 0; i < 4; ++i)
                #pragma unroll
                for (int j = 0; j < 4; ++j)
                    acc[i][j] = __builtin_amdgcn_mfma_f32_16x16x32_bf16(
                        af[i], bfr[j], acc[i][j], 0, 0, 0);
        }
    };

    const int NTK = K / 64;   // 16
    stage(0);
    __syncthreads();
    for (int kt = 0; kt < NTK - 1; ++kt) {
        stage((kt + 1) & 1);
        compute(kt & 1);
        __syncthreads();
    }
    compute((NTK - 1) & 1);
    // epilogue is register-only: no trailing barrier needed

    #pragma unroll
    for (int i = 0; i < 4; ++i) {
        #pragma unroll
        for (int j = 0; j < 4; ++j) {
            const int col = n0 + wc + j * 16 + lm;
            const float bv = b2f_raw(bias[col]);
            #pragma unroll
            for (int r = 0; r < 4; ++r) {
                const int row = m0 + wr + i * 16 + lq * 4 + r;
                const float v = acc[i][j][r] + bv;
                if constexpr (OBF)
                    ((__hip_bfloat16*)out)[(size_t)row * N + col] = __float2bfloat16(v);
                else
                    ((float*)out)[(size_t)row * N + col] = v;
            }
        }
    }
}

__global__ __launch_bounds__(256, 2)
void gemm2_kernel(const void* __restrict__ x_raw,
                  const void* __restrict__ pw_raw,
                  const void* __restrict__ pb_raw,
                  const unsigned short* __restrict__ attn,
                  const unsigned short* __restrict__ pwb,
                  const unsigned short* __restrict__ pbb,
                  void* __restrict__ out) {
    const bool isbf = detect_bf16((const unsigned int*)x_raw);
    const unsigned short* W = isbf ? (const unsigned short*)pw_raw : pwb;
    const unsigned short* bias = isbf ? (const unsigned short*)pb_raw : pbb;
    // XCD-chunked bijective swizzle (512 blocks, 64 per XCD)
    const int lin     = blockIdx.y * 8 + blockIdx.x;
    const int logical = (lin & 7) * 64 + (lin >> 3);
    const int n0      = (logical & 7) * 128;
    const int m0      = (logical >> 3) * 128;
    if (isbf) mfma_gemm_body64<true>(attn, W, bias, out, B_ * N_, C_, C_, m0, n0);
    else      mfma_gemm_body64<false>(attn, W, bias, out, B_ * N_, C_, C_, m0, n0);
}

// ---------------------------------------------------------------------------
// 3 dispatches: prep(convert + fused gather/wec/collapse) -> gemm1 -> gemm2.
// xh/wect/wrct global buffers deleted. ws high-water ~41 MB.
// ---------------------------------------------------------------------------
extern "C" void kernel_launch(void* const* d_in, const int* in_sizes, int n_in,
                              void* d_out, int out_size, void* d_ws, size_t ws_size,
                              hipStream_t stream) {
    (void)in_sizes; (void)n_in; (void)out_size; (void)ws_size;

    char* ws = (char*)d_ws;
    size_t off = 0;
    auto alloc = [&](size_t bytes) {
        char* p = ws + off;
        off += (bytes + 255) & ~(size_t)255;
        return p;
    };

    unsigned short* xb    = (unsigned short*)alloc((size_t)B_ * N_ * C_ * 2);   // 16.78 MB
    unsigned short* qkwb  = (unsigned short*)alloc((size_t)2 * C_ * C_ * 2);    // 4.19 MB
    unsigned short* pwb   = (unsigned short*)alloc((size_t)C_ * C_ * 2);        // 2.10 MB
    unsigned short* pbb   = (unsigned short*)alloc((size_t)C_ * 2);
    unsigned short* cwbb  = (unsigned short*)alloc((size_t)HD * 2);
    unsigned short* attn  = (unsigned short*)alloc((size_t)B_ * N_ * C_ * 2);   // 16.78 MB
    unsigned short* we2t  = (unsigned short*)alloc((size_t)B_ * H_ * HD * HD * 2);
    unsigned short* wr2t  = (unsigned short*)alloc((size_t)B_ * H_ * HD * HD * 2);

    const int M = B_ * N_;  // 8192

    // 1) prep: converts (skipped for bf16) + fused gather/wec/collapse
    CvtArgs ca;
    ca.src[0] = d_in[0]; ca.dst[0] = xb;   ca.size[0] = B_ * N_ * C_;
    ca.src[1] = d_in[1]; ca.dst[1] = qkwb; ca.size[1] = 2 * C_ * C_;
    ca.src[2] = d_in[2]; ca.dst[2] = pwb;  ca.size[2] = C_ * C_;
    ca.src[3] = d_in[3]; ca.dst[3] = pbb;  ca.size[3] = C_;
    ca.src[4] = d_in[7]; ca.dst[4] = cwbb; ca.size[4] = HD;
    fused_prep_kernel<<<dim3(2048, 3), 256, 0, stream>>>(
        ca, d_in[4], d_in[5], d_in[6], we2t, wr2t);

    // 2) fused qk-projection + l2norm + score -> attn
    gemm1_score_kernel<<<dim3(16, M / 128), 256, 0, stream>>>(
        d_in[0], d_in[1], d_in[7], xb, qkwb, cwbb, we2t, wr2t, attn);

    // 3) output projection: out = attn @ proj_w^T + proj_b
    gemm2_kernel<<<dim3(C_ / 128, M / 128), 256, 0, stream>>>(
        d_in[0], d_in[2], d_in[3], attn, pwb, pbb, d_out);
}

// Round 11
// 190.949 us; speedup vs baseline: 1.1233x; 1.1233x over previous
//
#include <hip/hip_runtime.h>
#include <hip/hip_bf16.h>

// Problem shapes (fixed by setup_inputs)
constexpr int B_  = 4;
constexpr int N_  = 2048;
constexpr int C_  = 1024;
constexpr int H_  = 16;
constexpr int HD  = 64;    // head dim
constexpr int LR  = 20;    // low rank
constexpr int RS  = 200;   // subsample length R
constexpr int RP  = 224;   // RS padded to multiple of 32 (zero-filled)
constexpr int RPAD = 232;  // LDS row pad for prep (2-way bank alias = free)

typedef __attribute__((ext_vector_type(8))) short bf16x8;
typedef __attribute__((ext_vector_type(4))) float f32x4;

// Counted-vmcnt wait + lgkmcnt drain + barrier (R3-verified semantics:
// no LDS op crosses a barrier; counted vmcnt keeps later tiles' loads in
// flight across it — never vmcnt(0) in the main loop).
#define WAITBAR6 asm volatile("s_waitcnt vmcnt(6) lgkmcnt(0)\n\ts_barrier" ::: "memory")
#define WAITBAR0 asm volatile("s_waitcnt vmcnt(0) lgkmcnt(0)\n\ts_barrier" ::: "memory")

__device__ __forceinline__ float b2f_raw(unsigned short u) {
    union { unsigned int i; float f; } v;
    v.i = ((unsigned int)u) << 16;
    return v.f;
}
__device__ __forceinline__ unsigned short f2b(float f) {
    __hip_bfloat16 h = __float2bfloat16(f);
    return *(unsigned short*)&h;
}
template <bool BF>
__device__ __forceinline__ float ldg(const void* p, size_t i) {
    if constexpr (BF) return b2f_raw(((const unsigned short*)p)[i]);
    else              return ((const float*)p)[i];
}

// async 16B global->LDS (wave-uniform LDS base; HW scatters lane i at +16*i)
__device__ __forceinline__ void async_load16(const unsigned short* g, unsigned short* l) {
    __builtin_amdgcn_global_load_lds(
        (const __attribute__((address_space(1))) unsigned int*)(const void*)g,
        (__attribute__((address_space(3))) unsigned int*)(void*)l,
        16, 0, 0);
}

// ---------------------------------------------------------------------------
// Inline dtype detect (deterministic function of x[0..1023]; all blocks in
// all kernels agree). Wave-uniform; ~4KB L2-hot read.
// ---------------------------------------------------------------------------
__device__ __forceinline__ bool detect_bf16(const unsigned int* __restrict__ x) {
    const int lane = threadIdx.x & 63;
    int cnt = 0;
    #pragma unroll
    for (int i = 0; i < 16; ++i) {
        const unsigned int w = x[lane * 16 + i];
        const unsigned int e = (w >> 7) & 0xFFu;
        cnt += (e >= 103u && e <= 140u) ? 1 : 0;
    }
    #pragma unroll
    for (int s = 1; s < 64; s <<= 1) cnt += __shfl_xor(cnt, s, 64);
    return cnt > 512;
}

// ---------------------------------------------------------------------------
// Fused prep (unchanged from round 10 — verified). Grid (2048, 3):
//  y == 0: convert x; y == 1: convert small buffers (both skipped when bf16)
//  y == 2: blocks 0..255 -> fused gather+wec+collapse -> we2t/wr2t directly.
// ---------------------------------------------------------------------------
struct CvtArgs {
    const void* src[5];
    unsigned short* dst[5];
    int size[5];
};

template <bool BF>
__device__ void gwc_body(const void* __restrict__ x_raw,
                         const void* __restrict__ we_raw,
                         const void* __restrict__ wr_raw,
                         const void* __restrict__ cw_raw,
                         unsigned short* __restrict__ we2t,
                         unsigned short* __restrict__ wr2t,
                         unsigned short* __restrict__ sx,   // [224*32]
                         unsigned short* __restrict__ sx2,  // [32*RPAD]
                         unsigned short* __restrict__ wl,   // [64*RPAD]
                         float* __restrict__ cwl,           // [64*20]
                         int blk) {
    const int bh    = blk >> 2;
    const int dhalf = (blk >> 1) & 1;
    const int qk    = blk & 1;
    const int b = bh >> 4;
    const int h = bh & 15;
    const int t    = threadIdx.x;
    const int wave = t >> 6;
    const int lane = t & 63;

    // (a) preload this block's cw slice as fp32 (qk selects e-offset)
    {
        const int dout = t >> 2;
        const int e0   = (t & 3) * 5;
        #pragma unroll
        for (int i = 0; i < 5; ++i)
            cwl[dout * LR + e0 + i] =
                ldg<BF>(cw_raw, (size_t)dout * 2 * LR + qk * LR + e0 + i);
    }

    // (b) gather fill into swizzled sx (verified round-6 pattern, unchanged)
    const int dlo = lane & 31;
    const int rhi = lane >> 5;     // 0/1
    for (int rd = wave; rd < 100; rd += 4) {
        const int r  = rd * 2 + rhi;
        const int ir = (r * (N_ - 1)) / (RS - 1);
        const size_t idx = ((size_t)b * N_ + ir) * C_ + h * HD + dhalf * 32 + dlo;
        unsigned short v;
        if constexpr (BF) v = ((const unsigned short*)x_raw)[idx];
        else              v = f2b(((const float*)x_raw)[idx]);
        sx[r * 32 + (dlo ^ (r & 31))] = v;
    }
    __syncthreads();   // cwl + sx ready

    // (c) wec slice: thread r computes wl[dout][r] = sum_e we*cw
    if (t < RP) {
        const int r = t;
        float w20[LR];
        if (r < RS) {
            const void* wsrc = qk ? wr_raw : we_raw;
            #pragma unroll
            for (int e = 0; e < LR; ++e)
                w20[e] = ldg<BF>(wsrc, ((size_t)h * RS + r) * LR + e);
        } else {
            #pragma unroll
            for (int e = 0; e < LR; ++e) w20[e] = 0.f;
        }
        for (int dout = 0; dout < HD; ++dout) {
            float s = 0.f;
            #pragma unroll
            for (int e = 0; e < LR; ++e) s += w20[e] * cwl[dout * LR + e];
            wl[dout * RPAD + r] = f2b(s);
        }
    }

    // (d) LDS transpose sx -> sx2[din][r]
    for (int o = t; o < 32 * RP; o += 256) {
        const int din = o / RP;
        const int r   = o % RP;
        const unsigned short v = (r < RS) ? sx[r * 32 + (din ^ (r & 31))]
                                          : (unsigned short)0;
        sx2[din * RPAD + r] = v;
    }
    __syncthreads();   // wl + sx2 ready

    // (e) collapse MFMA: wave w owns dout rows [w*16, w*16+16), K=224.
    const int lq = lane >> 4;
    const int lm = lane & 15;
    f32x4 acc[2];
    acc[0] = 0.f; acc[1] = 0.f;
    for (int ks = 0; ks < RP / 32; ++ks) {
        bf16x8 av = *(const bf16x8*)&wl[(wave * 16 + lm) * RPAD + ks * 32 + lq * 8];
        #pragma unroll
        for (int j = 0; j < 2; ++j) {
            bf16x8 bv = *(const bf16x8*)&sx2[(j * 16 + lm) * RPAD + ks * 32 + lq * 8];
            acc[j] = __builtin_amdgcn_mfma_f32_16x16x32_bf16(av, bv, acc[j], 0, 0, 0);
        }
    }
    unsigned short* dst = (qk ? wr2t : we2t) + (size_t)bh * HD * HD;
    #pragma unroll
    for (int j = 0; j < 2; ++j)
        #pragma unroll
        for (int r = 0; r < 4; ++r) {
            const int dout = wave * 16 + lq * 4 + r;
            const int din  = dhalf * 32 + j * 16 + lm;
            dst[dout * HD + din] = f2b(acc[j][r]);
        }
}

__global__ __launch_bounds__(256)
void fused_prep_kernel(CvtArgs args,
                       const void* __restrict__ we_raw,
                       const void* __restrict__ wr_raw,
                       const void* __restrict__ cw_raw,
                       unsigned short* __restrict__ we2t,
                       unsigned short* __restrict__ wr2t) {
    __shared__ __align__(16) unsigned short sx[RP * 32];     // 14.0 KB
    __shared__ __align__(16) unsigned short sx2[32 * RPAD];  // 14.5 KB
    __shared__ __align__(16) unsigned short wl[64 * RPAD];   // 29.0 KB
    __shared__ float cwl[64 * LR];                           //  5.0 KB
    const bool isbf = detect_bf16((const unsigned int*)args.src[0]);
    const int y = blockIdx.y;
    if (y == 0) {
        if (isbf) return;   // zero-copy: consumers read raw bf16 directly
        const int n4 = args.size[0] >> 2;
        const int stride = 2048 * 256;
        for (int i = blockIdx.x * 256 + threadIdx.x; i < n4; i += stride) {
            const float4 v = ((const float4*)args.src[0])[i];
            ushort4 o;
            o.x = f2b(v.x); o.y = f2b(v.y); o.z = f2b(v.z); o.w = f2b(v.w);
            ((ushort4*)args.dst[0])[i] = o;
        }
    } else if (y == 1) {
        if (isbf) return;
        const int n1 = args.size[1] >> 2;
        const int n2 = args.size[2] >> 2;
        const int n3 = args.size[3] >> 2;
        const int n4 = args.size[4] >> 2;
        const int tot = n1 + n2 + n3 + n4;
        const int stride = 2048 * 256;
        for (int i = blockIdx.x * 256 + threadIdx.x; i < tot; i += stride) {
            const float4* s; ushort4* d; int j;
            if (i < n1)                { s = (const float4*)args.src[1]; d = (ushort4*)args.dst[1]; j = i; }
            else if (i < n1 + n2)      { s = (const float4*)args.src[2]; d = (ushort4*)args.dst[2]; j = i - n1; }
            else if (i < n1 + n2 + n3) { s = (const float4*)args.src[3]; d = (ushort4*)args.dst[3]; j = i - n1 - n2; }
            else                       { s = (const float4*)args.src[4]; d = (ushort4*)args.dst[4]; j = i - n1 - n2 - n3; }
            const float4 v = s[j];
            ushort4 o;
            o.x = f2b(v.x); o.y = f2b(v.y); o.z = f2b(v.z); o.w = f2b(v.w);
            d[j] = o;
        }
    } else {
        const int blk = blockIdx.x;
        if (blk >= 256) return;
        if (isbf) gwc_body<true>(args.src[0], we_raw, wr_raw, cw_raw,
                                 we2t, wr2t, sx, sx2, wl, cwl, blk);
        else      gwc_body<false>(args.src[0], we_raw, wr_raw, cw_raw,
                                  we2t, wr2t, sx, sx2, wl, cwl, blk);
    }
}

// ---------------------------------------------------------------------------
// Fused gemm1 + l2norm + score. NEW this round: BM=256 x BN=128, 8 waves
// (512 threads), BK=64, THREE LDS K-tile buffers (144 KB), R3-verified
// counted-vmcnt rotation:
//   prologue: stage(0); stage(1)                        (12 loads in flight)
//   t<NT-2 : WAITBAR6; stage((t+2)%3); compute(t%3)
//   t=NT-2 : WAITBAR6;                 compute(t%3)
//   t=NT-1 : WAITBAR0;                 compute(t%3)
// Tile t's 6 loads were issued TWO phases (~2400 cyc of MFMA at 2 waves/SIMD)
// before use -> vmcnt wait ~free; loads never drain to 0 in the loop (T4).
// lgkmcnt(0)+barrier at each WAITBAR = proven-safe WAR discipline (R3 passed).
// Swizzle pair (source sunit / read cc) identical to the verified R6 scheme
// (same 64-col row geometry). k-monotonic accumulation -> bit-identical.
// ---------------------------------------------------------------------------
__global__ __launch_bounds__(512, 1)
void gemm1_score_kernel(const void* __restrict__ x_raw,
                        const void* __restrict__ qkw_raw,
                        const void* __restrict__ cwb_raw,
                        const unsigned short* __restrict__ xb,
                        const unsigned short* __restrict__ qkwb,
                        const unsigned short* __restrict__ cwbb,
                        const unsigned short* __restrict__ we2t,
                        const unsigned short* __restrict__ wr2t,
                        unsigned short* __restrict__ attn) {
    constexpr int QS = 72;
    // 3 bufs x (A 256x64 = 16384 sh + B 128x64 = 8192 sh) = 73728 sh = 144 KB
    __shared__ __align__(16) unsigned short pool[73728];
    unsigned short* qn = pool;              // phase 2: 256 x QS (36 KB)
    unsigned short* kn = pool + 256 * QS;   //          256 x QS

    const bool isbf = detect_bf16((const unsigned int*)x_raw);
    const unsigned short* xs  = isbf ? (const unsigned short*)x_raw   : xb;
    const unsigned short* qks = isbf ? (const unsigned short*)qkw_raw : qkwb;
    const unsigned short* cwb = isbf ? (const unsigned short*)cwb_raw : cwbb;

    const int t    = threadIdx.x;
    const int wave = t >> 6;            // 0..7
    const int lane = t & 63;
    // XCD-chunked bijective swizzle (512 blocks, 64 per XCD)
    const int lin     = blockIdx.y * 16 + blockIdx.x;   // grid (16, 32)
    const int logical = (lin & 7) * 64 + (lin >> 3);
    const int h       = logical & 15;
    const int mt      = logical >> 4;   // m-tile 0..31 (256 rows each)
    const int m0      = mt * 256;
    const int K       = C_;

    // staging: wave stages A rows [wave*32,+32) (4 loads) and B rows
    // [wave*16,+16) (2 loads). Source col-unit pre-swizzled (involution).
    const int srow  = lane >> 3;                    // 0..7
    const int sunit = (lane & 7) ^ srow;
    const unsigned short* gA = xs + (size_t)(m0 + wave * 32 + srow) * K + sunit * 8;
    const int vb0 = wave * 16 + srow;               // virtual B row 0..127
    const size_t brow = (vb0 < 64) ? (size_t)(h * HD + vb0)
                                   : (size_t)(C_ + h * HD + (vb0 - 64));
    const unsigned short* gB = qks + brow * K + sunit * 8;

    const int wr = (wave >> 1) * 64;    // row quadrant: 0,64,128,192
    const int wn = wave & 1;            // 0 = q cols, 1 = k cols
    const int lq = lane >> 4;
    const int lm = lane & 15;
    const int c0 = (lq ^ (lm & 7)) * 8; // swizzled read col, ks=0

    f32x4 acc[4][4];
    #pragma unroll
    for (int i = 0; i < 4; ++i)
        #pragma unroll
        for (int j = 0; j < 4; ++j) acc[i][j] = 0.f;

    auto stage = [&](int b) {
        unsigned short* dA = pool + b * 24576 + wave * 2048;
        unsigned short* dB = pool + b * 24576 + 16384 + wave * 1024;
        #pragma unroll
        for (int i = 0; i < 4; ++i)
            async_load16(gA + (size_t)i * 8 * K, dA + i * 512);
        #pragma unroll
        for (int i = 0; i < 2; ++i)
            async_load16(gB + (size_t)i * 8 * K, dB + i * 512);
        gA += 64; gB += 64;
    };
    auto compute = [&](int b) {
        const unsigned short* As = pool + b * 24576;
        const unsigned short* Bs = As + 16384;
        #pragma unroll
        for (int ks = 0; ks < 2; ++ks) {
            const int cc = c0 ^ (ks * 32);
            bf16x8 af[4], bfr[4];
            #pragma unroll
            for (int i = 0; i < 4; ++i)
                af[i] = *(const bf16x8*)&As[(wr + i * 16 + lm) * 64 + cc];
            #pragma unroll
            for (int j = 0; j < 4; ++j)
                bfr[j] = *(const bf16x8*)&Bs[(wn * 64 + j * 16 + lm) * 64 + cc];
            #pragma unroll
            for (int i = 0; i < 4; ++i)
                #pragma unroll
                for (int j = 0; j < 4; ++j)
                    acc[i][j] = __builtin_amdgcn_mfma_f32_16x16x32_bf16(
                        af[i], bfr[j], acc[i][j], 0, 0, 0);
        }
    };

    constexpr int NT = C_ / 64;    // 16 K-tiles
    stage(0); stage(1);
    for (int kt = 0; kt < NT; ++kt) {
        if (kt + 2 < NT)      { WAITBAR6; stage((kt + 2) % 3); }
        else if (kt + 1 < NT) { WAITBAR6; }
        else                  { WAITBAR0; }
        compute(kt % 3);
    }
    __syncthreads();               // all reads done before pool reuse

    // ---- phase 2a: per-row l2 norm + scaled bf16 store to LDS ----
    unsigned short* dst = (wn == 0) ? qn : kn;
    #pragma unroll
    for (int i = 0; i < 4; ++i) {
        float inv[4];
        #pragma unroll
        for (int r = 0; r < 4; ++r) {
            float s = 0.f;
            #pragma unroll
            for (int j = 0; j < 4; ++j) s += acc[i][j][r] * acc[i][j][r];
            s += __shfl_xor(s, 1, 64);
            s += __shfl_xor(s, 2, 64);
            s += __shfl_xor(s, 4, 64);
            s += __shfl_xor(s, 8, 64);
            inv[r] = 1.f / fmaxf(sqrtf(s), 1e-12f);
        }
        #pragma unroll
        for (int j = 0; j < 4; ++j)
            #pragma unroll
            for (int r = 0; r < 4; ++r) {
                const int row = wr + i * 16 + lq * 4 + r;   // 0..255
                dst[row * QS + j * 16 + lm] = f2b(acc[i][j][r] * inv[r]);
            }
    }
    __syncthreads();

    // ---- phase 2b: attn = qn@We2T^T + kn@Wr2T^T + cw_b (8 waves x 32 rows) ----
    const int b  = mt >> 3;                 // batch: 8 m-tiles per batch
    const int bh = b * H_ + h;
    const unsigned short* wq = we2t + (size_t)bh * HD * HD;
    const unsigned short* wk = wr2t + (size_t)bh * HD * HD;

    bf16x8 bq[2][4], bk[2][4];
    #pragma unroll
    for (int t2 = 0; t2 < 2; ++t2)
        #pragma unroll
        for (int j = 0; j < 4; ++j) {
            const int dout = j * 16 + lm;
            bq[t2][j] = *(const bf16x8*)&wq[dout * HD + t2 * 32 + lq * 8];
            bk[t2][j] = *(const bf16x8*)&wk[dout * HD + t2 * 32 + lq * 8];
        }

    f32x4 accS[2][4];
    #pragma unroll
    for (int rt = 0; rt < 2; ++rt)
        #pragma unroll
        for (int j = 0; j < 4; ++j) accS[rt][j] = 0.f;

    #pragma unroll
    for (int rt = 0; rt < 2; ++rt) {
        const int lr = wave * 32 + rt * 16 + lm;    // 0..255
        bf16x8 aq0 = *(const bf16x8*)&qn[lr * QS + lq * 8];
        bf16x8 aq1 = *(const bf16x8*)&qn[lr * QS + 32 + lq * 8];
        bf16x8 ak0 = *(const bf16x8*)&kn[lr * QS + lq * 8];
        bf16x8 ak1 = *(const bf16x8*)&kn[lr * QS + 32 + lq * 8];
        #pragma unroll
        for (int j = 0; j < 4; ++j) {
            accS[rt][j] = __builtin_amdgcn_mfma_f32_16x16x32_bf16(aq0, bq[0][j], accS[rt][j], 0, 0, 0);
            accS[rt][j] = __builtin_amdgcn_mfma_f32_16x16x32_bf16(aq1, bq[1][j], accS[rt][j], 0, 0, 0);
            accS[rt][j] = __builtin_amdgcn_mfma_f32_16x16x32_bf16(ak0, bk[0][j], accS[rt][j], 0, 0, 0);
            accS[rt][j] = __builtin_amdgcn_mfma_f32_16x16x32_bf16(ak1, bk[1][j], accS[rt][j], 0, 0, 0);
        }
    }

    #pragma unroll
    for (int rt = 0; rt < 2; ++rt)
        #pragma unroll
        for (int j = 0; j < 4; ++j) {
            const int dout = j * 16 + lm;
            const float bv = b2f_raw(cwb[dout]);
            #pragma unroll
            for (int r = 0; r < 4; ++r) {
                const int row = m0 + wave * 32 + rt * 16 + lq * 4 + r;
                attn[(size_t)row * C_ + h * HD + dout] = f2b(accS[rt][j][r] + bv);
            }
        }
}

// ---------------------------------------------------------------------------
// Output projection: same BM=256 x BN=128 3-buffer counted-vmcnt body.
// Grid 256 blocks = single full pass at 1 block/CU.
// ---------------------------------------------------------------------------
template <bool OBF>
__device__ void mfma_gemm_body3buf(const unsigned short* __restrict__ A,
                                   const unsigned short* __restrict__ W,
                                   const unsigned short* __restrict__ bias,
                                   void* __restrict__ out,
                                   int N, int K, int m0, int n0,
                                   unsigned short* pool) {
    const int t    = threadIdx.x;
    const int wave = t >> 6;
    const int lane = t & 63;

    const int srow  = lane >> 3;
    const int sunit = (lane & 7) ^ srow;
    const unsigned short* gA = A + (size_t)(m0 + wave * 32 + srow) * K + sunit * 8;
    const unsigned short* gB = W + (size_t)(n0 + wave * 16 + srow) * K + sunit * 8;

    const int wr = (wave >> 1) * 64;
    const int wn = wave & 1;
    const int lq = lane >> 4;
    const int lm = lane & 15;
    const int c0 = (lq ^ (lm & 7)) * 8;

    f32x4 acc[4][4];
    #pragma unroll
    for (int i = 0; i < 4; ++i)
        #pragma unroll
        for (int j = 0; j < 4; ++j) acc[i][j] = 0.f;

    auto stage = [&](int b) {
        unsigned short* dA = pool + b * 24576 + wave * 2048;
        unsigned short* dB = pool + b * 24576 + 16384 + wave * 1024;
        #pragma unroll
        for (int i = 0; i < 4; ++i)
            async_load16(gA + (size_t)i * 8 * K, dA + i * 512);
        #pragma unroll
        for (int i = 0; i < 2; ++i)
            async_load16(gB + (size_t)i * 8 * K, dB + i * 512);
        gA += 64; gB += 64;
    };
    auto compute = [&](int b) {
        const unsigned short* As = pool + b * 24576;
        const unsigned short* Bs = As + 16384;
        #pragma unroll
        for (int ks = 0; ks < 2; ++ks) {
            const int cc = c0 ^ (ks * 32);
            bf16x8 af[4], bfr[4];
            #pragma unroll
            for (int i = 0; i < 4; ++i)
                af[i] = *(const bf16x8*)&As[(wr + i * 16 + lm) * 64 + cc];
            #pragma unroll
            for (int j = 0; j < 4; ++j)
                bfr[j] = *(const bf16x8*)&Bs[(wn * 64 + j * 16 + lm) * 64 + cc];
            #pragma unroll
            for (int i = 0; i < 4; ++i)
                #pragma unroll
                for (int j = 0; j < 4; ++j)
                    acc[i][j] = __builtin_amdgcn_mfma_f32_16x16x32_bf16(
                        af[i], bfr[j], acc[i][j], 0, 0, 0);
        }
    };

    const int NT = K / 64;   // 16
    stage(0); stage(1);
    for (int kt = 0; kt < NT; ++kt) {
        if (kt + 2 < NT)      { WAITBAR6; stage((kt + 2) % 3); }
        else if (kt + 1 < NT) { WAITBAR6; }
        else                  { WAITBAR0; }
        compute(kt % 3);
    }
    // epilogue is register-only: no trailing barrier needed

    #pragma unroll
    for (int i = 0; i < 4; ++i) {
        #pragma unroll
        for (int j = 0; j < 4; ++j) {
            const int col = n0 + wn * 64 + j * 16 + lm;
            const float bv = b2f_raw(bias[col]);
            #pragma unroll
            for (int r = 0; r < 4; ++r) {
                const int row = m0 + wr + i * 16 + lq * 4 + r;
                const float v = acc[i][j][r] + bv;
                if constexpr (OBF)
                    ((__hip_bfloat16*)out)[(size_t)row * N + col] = __float2bfloat16(v);
                else
                    ((float*)out)[(size_t)row * N + col] = v;
            }
        }
    }
}

__global__ __launch_bounds__(512, 1)
void gemm2_kernel(const void* __restrict__ x_raw,
                  const void* __restrict__ pw_raw,
                  const void* __restrict__ pb_raw,
                  const unsigned short* __restrict__ attn,
                  const unsigned short* __restrict__ pwb,
                  const unsigned short* __restrict__ pbb,
                  void* __restrict__ out) {
    __shared__ __align__(16) unsigned short pool[73728];   // 144 KB
    const bool isbf = detect_bf16((const unsigned int*)x_raw);
    const unsigned short* W = isbf ? (const unsigned short*)pw_raw : pwb;
    const unsigned short* bias = isbf ? (const unsigned short*)pb_raw : pbb;
    // XCD-chunked bijective swizzle (256 blocks, 32 per XCD)
    const int lin     = blockIdx.y * 8 + blockIdx.x;    // grid (8, 32)
    const int logical = (lin & 7) * 32 + (lin >> 3);
    const int n0      = (logical & 7) * 128;
    const int m0      = (logical >> 3) * 256;
    if (isbf) mfma_gemm_body3buf<true>(attn, W, bias, out, C_, C_, m0, n0, pool);
    else      mfma_gemm_body3buf<false>(attn, W, bias, out, C_, C_, m0, n0, pool);
}

// ---------------------------------------------------------------------------
// 3 dispatches: prep(convert + fused gather/wec/collapse) -> gemm1 -> gemm2.
// ws high-water ~41 MB (< proven-safe 57.9 MB).
// ---------------------------------------------------------------------------
extern "C" void kernel_launch(void* const* d_in, const int* in_sizes, int n_in,
                              void* d_out, int out_size, void* d_ws, size_t ws_size,
                              hipStream_t stream) {
    (void)in_sizes; (void)n_in; (void)out_size; (void)ws_size;

    char* ws = (char*)d_ws;
    size_t off = 0;
    auto alloc = [&](size_t bytes) {
        char* p = ws + off;
        off += (bytes + 255) & ~(size_t)255;
        return p;
    };

    unsigned short* xb    = (unsigned short*)alloc((size_t)B_ * N_ * C_ * 2);   // 16.78 MB
    unsigned short* qkwb  = (unsigned short*)alloc((size_t)2 * C_ * C_ * 2);    // 4.19 MB
    unsigned short* pwb   = (unsigned short*)alloc((size_t)C_ * C_ * 2);        // 2.10 MB
    unsigned short* pbb   = (unsigned short*)alloc((size_t)C_ * 2);
    unsigned short* cwbb  = (unsigned short*)alloc((size_t)HD * 2);
    unsigned short* attn  = (unsigned short*)alloc((size_t)B_ * N_ * C_ * 2);   // 16.78 MB
    unsigned short* we2t  = (unsigned short*)alloc((size_t)B_ * H_ * HD * HD * 2);
    unsigned short* wr2t  = (unsigned short*)alloc((size_t)B_ * H_ * HD * HD * 2);

    // 1) prep: converts (skipped for bf16) + fused gather/wec/collapse
    CvtArgs ca;
    ca.src[0] = d_in[0]; ca.dst[0] = xb;   ca.size[0] = B_ * N_ * C_;
    ca.src[1] = d_in[1]; ca.dst[1] = qkwb; ca.size[1] = 2 * C_ * C_;
    ca.src[2] = d_in[2]; ca.dst[2] = pwb;  ca.size[2] = C_ * C_;
    ca.src[3] = d_in[3]; ca.dst[3] = pbb;  ca.size[3] = C_;
    ca.src[4] = d_in[7]; ca.dst[4] = cwbb; ca.size[4] = HD;
    fused_prep_kernel<<<dim3(2048, 3), 256, 0, stream>>>(
        ca, d_in[4], d_in[5], d_in[6], we2t, wr2t);

    // 2) fused qk-projection + l2norm + score -> attn (512 blocks x 512 thr)
    gemm1_score_kernel<<<dim3(16, 32), 512, 0, stream>>>(
        d_in[0], d_in[1], d_in[7], xb, qkwb, cwbb, we2t, wr2t, attn);

    // 3) output projection (256 blocks x 512 thr)
    gemm2_kernel<<<dim3(8, 32), 512, 0, stream>>>(
        d_in[0], d_in[2], d_in[3], attn, pwb, pbb, d_out);
}

// Round 12
// 190.421 us; speedup vs baseline: 1.1264x; 1.0028x over previous
//
#include <hip/hip_runtime.h>
#include <hip/hip_bf16.h>

// Problem shapes (fixed by setup_inputs)
constexpr int B_  = 4;
constexpr int N_  = 2048;
constexpr int C_  = 1024;
constexpr int H_  = 16;
constexpr int HD  = 64;    // head dim
constexpr int LR  = 20;    // low rank
constexpr int RS  = 200;   // subsample length R
constexpr int RP  = 224;   // RS padded to multiple of 32 (zero-filled)
constexpr int RPAD = 232;  // LDS row pad for prep (2-way bank alias = free)

typedef __attribute__((ext_vector_type(8))) short bf16x8;
typedef __attribute__((ext_vector_type(4))) float f32x4;

// Counted-vmcnt wait + lgkmcnt drain + barrier (R3/R11-verified semantics)
#define WAITBAR6 asm volatile("s_waitcnt vmcnt(6) lgkmcnt(0)\n\ts_barrier" ::: "memory")
#define WAITBAR0 asm volatile("s_waitcnt vmcnt(0) lgkmcnt(0)\n\ts_barrier" ::: "memory")

__device__ __forceinline__ float b2f_raw(unsigned short u) {
    union { unsigned int i; float f; } v;
    v.i = ((unsigned int)u) << 16;
    return v.f;
}
__device__ __forceinline__ unsigned short f2b(float f) {
    __hip_bfloat16 h = __float2bfloat16(f);
    return *(unsigned short*)&h;
}
template <bool BF>
__device__ __forceinline__ float ldg(const void* p, size_t i) {
    if constexpr (BF) return b2f_raw(((const unsigned short*)p)[i]);
    else              return ((const float*)p)[i];
}

// async 16B global->LDS (wave-uniform LDS base; HW scatters lane i at +16*i)
__device__ __forceinline__ void async_load16(const unsigned short* g, unsigned short* l) {
    __builtin_amdgcn_global_load_lds(
        (const __attribute__((address_space(1))) unsigned int*)(const void*)g,
        (__attribute__((address_space(3))) unsigned int*)(void*)l,
        16, 0, 0);
}

// ---------------------------------------------------------------------------
// Inline dtype detect (deterministic function of x[0..1023]; all blocks in
// all kernels agree). Wave-uniform; ~4KB L2-hot read.
// ---------------------------------------------------------------------------
__device__ __forceinline__ bool detect_bf16(const unsigned int* __restrict__ x) {
    const int lane = threadIdx.x & 63;
    int cnt = 0;
    #pragma unroll
    for (int i = 0; i < 16; ++i) {
        const unsigned int w = x[lane * 16 + i];
        const unsigned int e = (w >> 7) & 0xFFu;
        cnt += (e >= 103u && e <= 140u) ? 1 : 0;
    }
    #pragma unroll
    for (int s = 1; s < 64; s <<= 1) cnt += __shfl_xor(cnt, s, 64);
    return cnt > 512;
}

// ---------------------------------------------------------------------------
// Fused prep (unchanged from rounds 10/11 — verified). Grid (2048, 3):
//  y == 0: convert x; y == 1: convert small buffers (both skipped when bf16)
//  y == 2: blocks 0..255 -> fused gather+wec+collapse -> we2t/wr2t directly.
// ---------------------------------------------------------------------------
struct CvtArgs {
    const void* src[5];
    unsigned short* dst[5];
    int size[5];
};

template <bool BF>
__device__ void gwc_body(const void* __restrict__ x_raw,
                         const void* __restrict__ we_raw,
                         const void* __restrict__ wr_raw,
                         const void* __restrict__ cw_raw,
                         unsigned short* __restrict__ we2t,
                         unsigned short* __restrict__ wr2t,
                         unsigned short* __restrict__ sx,   // [224*32]
                         unsigned short* __restrict__ sx2,  // [32*RPAD]
                         unsigned short* __restrict__ wl,   // [64*RPAD]
                         float* __restrict__ cwl,           // [64*20]
                         int blk) {
    const int bh    = blk >> 2;
    const int dhalf = (blk >> 1) & 1;
    const int qk    = blk & 1;
    const int b = bh >> 4;
    const int h = bh & 15;
    const int t    = threadIdx.x;
    const int wave = t >> 6;
    const int lane = t & 63;

    // (a) preload this block's cw slice as fp32 (qk selects e-offset)
    {
        const int dout = t >> 2;
        const int e0   = (t & 3) * 5;
        #pragma unroll
        for (int i = 0; i < 5; ++i)
            cwl[dout * LR + e0 + i] =
                ldg<BF>(cw_raw, (size_t)dout * 2 * LR + qk * LR + e0 + i);
    }

    // (b) gather fill into swizzled sx (verified round-6 pattern, unchanged)
    const int dlo = lane & 31;
    const int rhi = lane >> 5;     // 0/1
    for (int rd = wave; rd < 100; rd += 4) {
        const int r  = rd * 2 + rhi;
        const int ir = (r * (N_ - 1)) / (RS - 1);
        const size_t idx = ((size_t)b * N_ + ir) * C_ + h * HD + dhalf * 32 + dlo;
        unsigned short v;
        if constexpr (BF) v = ((const unsigned short*)x_raw)[idx];
        else              v = f2b(((const float*)x_raw)[idx]);
        sx[r * 32 + (dlo ^ (r & 31))] = v;
    }
    __syncthreads();   // cwl + sx ready

    // (c) wec slice: thread r computes wl[dout][r] = sum_e we*cw
    if (t < RP) {
        const int r = t;
        float w20[LR];
        if (r < RS) {
            const void* wsrc = qk ? wr_raw : we_raw;
            #pragma unroll
            for (int e = 0; e < LR; ++e)
                w20[e] = ldg<BF>(wsrc, ((size_t)h * RS + r) * LR + e);
        } else {
            #pragma unroll
            for (int e = 0; e < LR; ++e) w20[e] = 0.f;
        }
        for (int dout = 0; dout < HD; ++dout) {
            float s = 0.f;
            #pragma unroll
            for (int e = 0; e < LR; ++e) s += w20[e] * cwl[dout * LR + e];
            wl[dout * RPAD + r] = f2b(s);
        }
    }

    // (d) LDS transpose sx -> sx2[din][r]
    for (int o = t; o < 32 * RP; o += 256) {
        const int din = o / RP;
        const int r   = o % RP;
        const unsigned short v = (r < RS) ? sx[r * 32 + (din ^ (r & 31))]
                                          : (unsigned short)0;
        sx2[din * RPAD + r] = v;
    }
    __syncthreads();   // wl + sx2 ready

    // (e) collapse MFMA: wave w owns dout rows [w*16, w*16+16), K=224.
    const int lq = lane >> 4;
    const int lm = lane & 15;
    f32x4 acc[2];
    acc[0] = 0.f; acc[1] = 0.f;
    for (int ks = 0; ks < RP / 32; ++ks) {
        bf16x8 av = *(const bf16x8*)&wl[(wave * 16 + lm) * RPAD + ks * 32 + lq * 8];
        #pragma unroll
        for (int j = 0; j < 2; ++j) {
            bf16x8 bv = *(const bf16x8*)&sx2[(j * 16 + lm) * RPAD + ks * 32 + lq * 8];
            acc[j] = __builtin_amdgcn_mfma_f32_16x16x32_bf16(av, bv, acc[j], 0, 0, 0);
        }
    }
    unsigned short* dst = (qk ? wr2t : we2t) + (size_t)bh * HD * HD;
    #pragma unroll
    for (int j = 0; j < 2; ++j)
        #pragma unroll
        for (int r = 0; r < 4; ++r) {
            const int dout = wave * 16 + lq * 4 + r;
            const int din  = dhalf * 32 + j * 16 + lm;
            dst[dout * HD + din] = f2b(acc[j][r]);
        }
}

__global__ __launch_bounds__(256)
void fused_prep_kernel(CvtArgs args,
                       const void* __restrict__ we_raw,
                       const void* __restrict__ wr_raw,
                       const void* __restrict__ cw_raw,
                       unsigned short* __restrict__ we2t,
                       unsigned short* __restrict__ wr2t) {
    __shared__ __align__(16) unsigned short sx[RP * 32];     // 14.0 KB
    __shared__ __align__(16) unsigned short sx2[32 * RPAD];  // 14.5 KB
    __shared__ __align__(16) unsigned short wl[64 * RPAD];   // 29.0 KB
    __shared__ float cwl[64 * LR];                           //  5.0 KB
    const bool isbf = detect_bf16((const unsigned int*)args.src[0]);
    const int y = blockIdx.y;
    if (y == 0) {
        if (isbf) return;   // zero-copy: consumers read raw bf16 directly
        const int n4 = args.size[0] >> 2;
        const int stride = 2048 * 256;
        for (int i = blockIdx.x * 256 + threadIdx.x; i < n4; i += stride) {
            const float4 v = ((const float4*)args.src[0])[i];
            ushort4 o;
            o.x = f2b(v.x); o.y = f2b(v.y); o.z = f2b(v.z); o.w = f2b(v.w);
            ((ushort4*)args.dst[0])[i] = o;
        }
    } else if (y == 1) {
        if (isbf) return;
        const int n1 = args.size[1] >> 2;
        const int n2 = args.size[2] >> 2;
        const int n3 = args.size[3] >> 2;
        const int n4 = args.size[4] >> 2;
        const int tot = n1 + n2 + n3 + n4;
        const int stride = 2048 * 256;
        for (int i = blockIdx.x * 256 + threadIdx.x; i < tot; i += stride) {
            const float4* s; ushort4* d; int j;
            if (i < n1)                { s = (const float4*)args.src[1]; d = (ushort4*)args.dst[1]; j = i; }
            else if (i < n1 + n2)      { s = (const float4*)args.src[2]; d = (ushort4*)args.dst[2]; j = i - n1; }
            else if (i < n1 + n2 + n3) { s = (const float4*)args.src[3]; d = (ushort4*)args.dst[3]; j = i - n1 - n2; }
            else                       { s = (const float4*)args.src[4]; d = (ushort4*)args.dst[4]; j = i - n1 - n2 - n3; }
            const float4 v = s[j];
            ushort4 o;
            o.x = f2b(v.x); o.y = f2b(v.y); o.z = f2b(v.z); o.w = f2b(v.w);
            d[j] = o;
        }
    } else {
        const int blk = blockIdx.x;
        if (blk >= 256) return;
        if (isbf) gwc_body<true>(args.src[0], we_raw, wr_raw, cw_raw,
                                 we2t, wr2t, sx, sx2, wl, cwl, blk);
        else      gwc_body<false>(args.src[0], we_raw, wr_raw, cw_raw,
                                  we2t, wr2t, sx, sx2, wl, cwl, blk);
    }
}

// ---------------------------------------------------------------------------
// Fused gemm1 + l2norm + score. EXACT round-10 body (verified, 52.0us):
// 128x128 tile, 4 waves, BK=64 dbuf, T3-minimum __syncthreads schedule,
// both-sides swizzle, XCD-chunked 1024-block grid, 2 blocks/CU.
// ---------------------------------------------------------------------------
__global__ __launch_bounds__(256, 2)
void gemm1_score_kernel(const void* __restrict__ x_raw,
                        const void* __restrict__ qkw_raw,
                        const void* __restrict__ cwb_raw,
                        const unsigned short* __restrict__ xb,
                        const unsigned short* __restrict__ qkwb,
                        const unsigned short* __restrict__ cwbb,
                        const unsigned short* __restrict__ we2t,
                        const unsigned short* __restrict__ wr2t,
                        unsigned short* __restrict__ attn) {
    constexpr int QS = 72;
    __shared__ __align__(16) unsigned short pool[32768];  // 64 KB
    unsigned short* const AsBase = pool;          // 2 x 128x64 A tiles (32 KB)
    unsigned short* const BsBase = pool + 16384;  // 2 x 128x64 B tiles (32 KB)
    unsigned short* qn = pool;                    // phase 2: 128xQS
    unsigned short* kn = pool + 128 * QS;

    const bool isbf = detect_bf16((const unsigned int*)x_raw);
    const unsigned short* xs  = isbf ? (const unsigned short*)x_raw   : xb;
    const unsigned short* qks = isbf ? (const unsigned short*)qkw_raw : qkwb;
    const unsigned short* cwb = isbf ? (const unsigned short*)cwb_raw : cwbb;

    const int t    = threadIdx.x;
    const int wave = t >> 6;
    const int lane = t & 63;
    // XCD-chunked bijective swizzle (1024 blocks, 128 per XCD)
    const int lin     = blockIdx.y * 16 + blockIdx.x;
    const int logical = (lin & 7) * 128 + (lin >> 3);
    const int h       = logical & 15;
    const int mt      = logical >> 4;       // m-tile 0..63
    const int m0      = mt * 128;
    const int K       = C_;

    const int srow  = lane >> 3;                    // 0..7
    const int sunit = (lane & 7) ^ srow;            // involutive swizzle
    const unsigned short* gA = xs + (size_t)(m0 + wave * 32 + srow) * K + sunit * 8;
    const int vb = wave * 32;                       // virtual B row 0..127
    const size_t brow = (vb < 64) ? (size_t)(h * HD + vb)
                                  : (size_t)(C_ + h * HD + (vb - 64));
    const unsigned short* gB = qks + (brow + srow) * K + sunit * 8;

    const int wr = (wave >> 1) * 64;        // row quadrant
    const int wc = (wave & 1) * 64;         // col quadrant: 0 = q, 64 = k
    const int lq = lane >> 4;
    const int lm = lane & 15;
    const int c0 = (lq ^ (lm & 7)) * 8;     // swizzled read col, ks=0

    f32x4 acc[4][4];
    #pragma unroll
    for (int i = 0; i < 4; ++i)
        #pragma unroll
        for (int j = 0; j < 4; ++j) acc[i][j] = 0.f;

    auto stage = [&](int buf) {
        unsigned short* dA = AsBase + buf * 8192 + wave * 2048;
        unsigned short* dB = BsBase + buf * 8192 + wave * 2048;
        #pragma unroll
        for (int i = 0; i < 4; ++i) {
            async_load16(gA + (size_t)i * 8 * K, dA + i * 512);
            async_load16(gB + (size_t)i * 8 * K, dB + i * 512);
        }
        gA += 64; gB += 64;
    };
    auto compute = [&](int buf) {
        const unsigned short* As = AsBase + buf * 8192;
        const unsigned short* Bs = BsBase + buf * 8192;
        #pragma unroll
        for (int ks = 0; ks < 2; ++ks) {
            const int cc = c0 ^ (ks * 32);
            bf16x8 af[4], bfr[4];
            #pragma unroll
            for (int i = 0; i < 4; ++i)
                af[i] = *(const bf16x8*)&As[(wr + i * 16 + lm) * 64 + cc];
            #pragma unroll
            for (int j = 0; j < 4; ++j)
                bfr[j] = *(const bf16x8*)&Bs[(wc + j * 16 + lm) * 64 + cc];
            #pragma unroll
            for (int i = 0; i < 4; ++i)
                #pragma unroll
                for (int j = 0; j < 4; ++j)
                    acc[i][j] = __builtin_amdgcn_mfma_f32_16x16x32_bf16(
                        af[i], bfr[j], acc[i][j], 0, 0, 0);
        }
    };

    constexpr int NTK = C_ / 64;   // 16 K-tiles
    stage(0);
    __syncthreads();
    for (int kt = 0; kt < NTK - 1; ++kt) {
        stage((kt + 1) & 1);       // prefetch next tile (other buffer)
        compute(kt & 1);           // 32 MFMA + 16 ds_read under the prefetch
        __syncthreads();           // drains vmcnt+lgkm: next tile ready, reads done
    }
    compute((NTK - 1) & 1);
    __syncthreads();               // before pool reuse by phase 2

    // ---- phase 2a: per-row l2 norm + scaled bf16 store to LDS ----
    unsigned short* dst = (wc == 0) ? qn : kn;
    #pragma unroll
    for (int i = 0; i < 4; ++i) {
        float inv[4];
        #pragma unroll
        for (int r = 0; r < 4; ++r) {
            float s = 0.f;
            #pragma unroll
            for (int j = 0; j < 4; ++j) s += acc[i][j][r] * acc[i][j][r];
            s += __shfl_xor(s, 1, 64);
            s += __shfl_xor(s, 2, 64);
            s += __shfl_xor(s, 4, 64);
            s += __shfl_xor(s, 8, 64);
            inv[r] = 1.f / fmaxf(sqrtf(s), 1e-12f);
        }
        #pragma unroll
        for (int j = 0; j < 4; ++j)
            #pragma unroll
            for (int r = 0; r < 4; ++r) {
                const int row = wr + i * 16 + lq * 4 + r;
                dst[row * QS + j * 16 + lm] = f2b(acc[i][j][r] * inv[r]);
            }
    }
    __syncthreads();

    // ---- phase 2b: attn = qn@We2T^T + kn@Wr2T^T + cw_b ----
    const int b  = mt >> 4;
    const int bh = b * H_ + h;
    const unsigned short* wq = we2t + (size_t)bh * HD * HD;
    const unsigned short* wk = wr2t + (size_t)bh * HD * HD;

    bf16x8 bq[2][4], bk[2][4];
    #pragma unroll
    for (int t2 = 0; t2 < 2; ++t2)
        #pragma unroll
        for (int j = 0; j < 4; ++j) {
            const int dout = j * 16 + lm;
            bq[t2][j] = *(const bf16x8*)&wq[dout * HD + t2 * 32 + lq * 8];
            bk[t2][j] = *(const bf16x8*)&wk[dout * HD + t2 * 32 + lq * 8];
        }

    f32x4 accS[2][4];
    #pragma unroll
    for (int rt = 0; rt < 2; ++rt)
        #pragma unroll
        for (int j = 0; j < 4; ++j) accS[rt][j] = 0.f;

    #pragma unroll
    for (int rt = 0; rt < 2; ++rt) {
        const int lr = wave * 32 + rt * 16 + lm;
        bf16x8 aq0 = *(const bf16x8*)&qn[lr * QS + lq * 8];
        bf16x8 aq1 = *(const bf16x8*)&qn[lr * QS + 32 + lq * 8];
        bf16x8 ak0 = *(const bf16x8*)&kn[lr * QS + lq * 8];
        bf16x8 ak1 = *(const bf16x8*)&kn[lr * QS + 32 + lq * 8];
        #pragma unroll
        for (int j = 0; j < 4; ++j) {
            accS[rt][j] = __builtin_amdgcn_mfma_f32_16x16x32_bf16(aq0, bq[0][j], accS[rt][j], 0, 0, 0);
            accS[rt][j] = __builtin_amdgcn_mfma_f32_16x16x32_bf16(aq1, bq[1][j], accS[rt][j], 0, 0, 0);
            accS[rt][j] = __builtin_amdgcn_mfma_f32_16x16x32_bf16(ak0, bk[0][j], accS[rt][j], 0, 0, 0);
            accS[rt][j] = __builtin_amdgcn_mfma_f32_16x16x32_bf16(ak1, bk[1][j], accS[rt][j], 0, 0, 0);
        }
    }

    #pragma unroll
    for (int rt = 0; rt < 2; ++rt)
        #pragma unroll
        for (int j = 0; j < 4; ++j) {
            const int dout = j * 16 + lm;
            const float bv = b2f_raw(cwb[dout]);
            #pragma unroll
            for (int r = 0; r < 4; ++r) {
                const int row = m0 + wave * 32 + rt * 16 + lq * 4 + r;
                attn[(size_t)row * C_ + h * HD + dout] = f2b(accS[rt][j][r] + bv);
            }
        }
}

// ---------------------------------------------------------------------------
// Output projection: EXACT round-11 body (verified): BM=256 x BN=128,
// 8 waves, 3 LDS buffers (144 KB), counted-vmcnt rotation, 256 blocks.
// ---------------------------------------------------------------------------
template <bool OBF>
__device__ void mfma_gemm_body3buf(const unsigned short* __restrict__ A,
                                   const unsigned short* __restrict__ W,
                                   const unsigned short* __restrict__ bias,
                                   void* __restrict__ out,
                                   int N, int K, int m0, int n0,
                                   unsigned short* pool) {
    const int t    = threadIdx.x;
    const int wave = t >> 6;
    const int lane = t & 63;

    const int srow  = lane >> 3;
    const int sunit = (lane & 7) ^ srow;
    const unsigned short* gA = A + (size_t)(m0 + wave * 32 + srow) * K + sunit * 8;
    const unsigned short* gB = W + (size_t)(n0 + wave * 16 + srow) * K + sunit * 8;

    const int wr = (wave >> 1) * 64;
    const int wn = wave & 1;
    const int lq = lane >> 4;
    const int lm = lane & 15;
    const int c0 = (lq ^ (lm & 7)) * 8;

    f32x4 acc[4][4];
    #pragma unroll
    for (int i = 0; i < 4; ++i)
        #pragma unroll
        for (int j = 0; j < 4; ++j) acc[i][j] = 0.f;

    auto stage = [&](int b) {
        unsigned short* dA = pool + b * 24576 + wave * 2048;
        unsigned short* dB = pool + b * 24576 + 16384 + wave * 1024;
        #pragma unroll
        for (int i = 0; i < 4; ++i)
            async_load16(gA + (size_t)i * 8 * K, dA + i * 512);
        #pragma unroll
        for (int i = 0; i < 2; ++i)
            async_load16(gB + (size_t)i * 8 * K, dB + i * 512);
        gA += 64; gB += 64;
    };
    auto compute = [&](int b) {
        const unsigned short* As = pool + b * 24576;
        const unsigned short* Bs = As + 16384;
        #pragma unroll
        for (int ks = 0; ks < 2; ++ks) {
            const int cc = c0 ^ (ks * 32);
            bf16x8 af[4], bfr[4];
            #pragma unroll
            for (int i = 0; i < 4; ++i)
                af[i] = *(const bf16x8*)&As[(wr + i * 16 + lm) * 64 + cc];
            #pragma unroll
            for (int j = 0; j < 4; ++j)
                bfr[j] = *(const bf16x8*)&Bs[(wn * 64 + j * 16 + lm) * 64 + cc];
            #pragma unroll
            for (int i = 0; i < 4; ++i)
                #pragma unroll
                for (int j = 0; j < 4; ++j)
                    acc[i][j] = __builtin_amdgcn_mfma_f32_16x16x32_bf16(
                        af[i], bfr[j], acc[i][j], 0, 0, 0);
        }
    };

    const int NT = K / 64;   // 16
    stage(0); stage(1);
    for (int kt = 0; kt < NT; ++kt) {
        if (kt + 2 < NT)      { WAITBAR6; stage((kt + 2) % 3); }
        else if (kt + 1 < NT) { WAITBAR6; }
        else                  { WAITBAR0; }
        compute(kt % 3);
    }
    // epilogue is register-only: no trailing barrier needed

    #pragma unroll
    for (int i = 0; i < 4; ++i) {
        #pragma unroll
        for (int j = 0; j < 4; ++j) {
            const int col = n0 + wn * 64 + j * 16 + lm;
            const float bv = b2f_raw(bias[col]);
            #pragma unroll
            for (int r = 0; r < 4; ++r) {
                const int row = m0 + wr + i * 16 + lq * 4 + r;
                const float v = acc[i][j][r] + bv;
                if constexpr (OBF)
                    ((__hip_bfloat16*)out)[(size_t)row * N + col] = __float2bfloat16(v);
                else
                    ((float*)out)[(size_t)row * N + col] = v;
            }
        }
    }
}

__global__ __launch_bounds__(512, 1)
void gemm2_kernel(const void* __restrict__ x_raw,
                  const void* __restrict__ pw_raw,
                  const void* __restrict__ pb_raw,
                  const unsigned short* __restrict__ attn,
                  const unsigned short* __restrict__ pwb,
                  const unsigned short* __restrict__ pbb,
                  void* __restrict__ out) {
    __shared__ __align__(16) unsigned short pool[73728];   // 144 KB
    const bool isbf = detect_bf16((const unsigned int*)x_raw);
    const unsigned short* W = isbf ? (const unsigned short*)pw_raw : pwb;
    const unsigned short* bias = isbf ? (const unsigned short*)pb_raw : pbb;
    // XCD-chunked bijective swizzle (256 blocks, 32 per XCD)
    const int lin     = blockIdx.y * 8 + blockIdx.x;    // grid (8, 32)
    const int logical = (lin & 7) * 32 + (lin >> 3);
    const int n0      = (logical & 7) * 128;
    const int m0      = (logical >> 3) * 256;
    if (isbf) mfma_gemm_body3buf<true>(attn, W, bias, out, C_, C_, m0, n0, pool);
    else      mfma_gemm_body3buf<false>(attn, W, bias, out, C_, C_, m0, n0, pool);
}

// ---------------------------------------------------------------------------
// 3 dispatches: prep(convert + fused gather/wec/collapse) -> gemm1 -> gemm2.
// ws high-water ~41 MB (< proven-safe 57.9 MB).
// ---------------------------------------------------------------------------
extern "C" void kernel_launch(void* const* d_in, const int* in_sizes, int n_in,
                              void* d_out, int out_size, void* d_ws, size_t ws_size,
                              hipStream_t stream) {
    (void)in_sizes; (void)n_in; (void)out_size; (void)ws_size;

    char* ws = (char*)d_ws;
    size_t off = 0;
    auto alloc = [&](size_t bytes) {
        char* p = ws + off;
        off += (bytes + 255) & ~(size_t)255;
        return p;
    };

    unsigned short* xb    = (unsigned short*)alloc((size_t)B_ * N_ * C_ * 2);   // 16.78 MB
    unsigned short* qkwb  = (unsigned short*)alloc((size_t)2 * C_ * C_ * 2);    // 4.19 MB
    unsigned short* pwb   = (unsigned short*)alloc((size_t)C_ * C_ * 2);        // 2.10 MB
    unsigned short* pbb   = (unsigned short*)alloc((size_t)C_ * 2);
    unsigned short* cwbb  = (unsigned short*)alloc((size_t)HD * 2);
    unsigned short* attn  = (unsigned short*)alloc((size_t)B_ * N_ * C_ * 2);   // 16.78 MB
    unsigned short* we2t  = (unsigned short*)alloc((size_t)B_ * H_ * HD * HD * 2);
    unsigned short* wr2t  = (unsigned short*)alloc((size_t)B_ * H_ * HD * HD * 2);

    const int M = B_ * N_;  // 8192

    // 1) prep: converts (skipped for bf16) + fused gather/wec/collapse
    CvtArgs ca;
    ca.src[0] = d_in[0]; ca.dst[0] = xb;   ca.size[0] = B_ * N_ * C_;
    ca.src[1] = d_in[1]; ca.dst[1] = qkwb; ca.size[1] = 2 * C_ * C_;
    ca.src[2] = d_in[2]; ca.dst[2] = pwb;  ca.size[2] = C_ * C_;
    ca.src[3] = d_in[3]; ca.dst[3] = pbb;  ca.size[3] = C_;
    ca.src[4] = d_in[7]; ca.dst[4] = cwbb; ca.size[4] = HD;
    fused_prep_kernel<<<dim3(2048, 3), 256, 0, stream>>>(
        ca, d_in[4], d_in[5], d_in[6], we2t, wr2t);

    // 2) fused qk-projection + l2norm + score -> attn (1024 blocks x 256 thr)
    gemm1_score_kernel<<<dim3(16, M / 128), 256, 0, stream>>>(
        d_in[0], d_in[1], d_in[7], xb, qkwb, cwbb, we2t, wr2t, attn);

    // 3) output projection (256 blocks x 512 thr)
    gemm2_kernel<<<dim3(8, 32), 512, 0, stream>>>(
        d_in[0], d_in[2], d_in[3], attn, pwb, pbb, d_out);
}